// Round 4
// baseline (935.698 us; speedup 1.0000x reference)
//
#include <hip/hip_runtime.h>
#include <hip/hip_bf16.h>
#include <stdint.h>

#define NVOX 131072
#define CCH  128
#define EPSV 1e-4f

typedef __bf16 bf16_t;
typedef bf16_t bf16x8 __attribute__((ext_vector_type(8)));
typedef bf16_t bf16x4 __attribute__((ext_vector_type(4)));
typedef float  f32x4  __attribute__((ext_vector_type(4)));

// swizzled f32 accumulator index: breaks the row*128 bank alignment
__device__ __forceinline__ int accIdx(int row, int col) {
    return (row << 7) + ((((col >> 2) + row) & 31) << 2) + (col & 3);
}

// ---------- prep: features f32 -> bf16 ----------
__global__ void k_prep_feat(const float* __restrict__ f, bf16_t* __restrict__ fb) {
    int i = blockIdx.x * 256 + threadIdx.x;      // over N*C/4 = 4194304
    const float4* f4 = (const float4*)f;
    float4 v = f4[i];
    bf16x4 o;
    o[0] = (bf16_t)v.x; o[1] = (bf16_t)v.y; o[2] = (bf16_t)v.z; o[3] = (bf16_t)v.w;
    ((bf16x4*)fb)[i] = o;
}

// ---------- prep: zero pad rows + stats ----------
__global__ void k_prep_misc(bf16_t* featb, bf16_t* y1, bf16_t* y2, float* stats) {
    int t = threadIdx.x;
    if (t < 128) {
        featb[(size_t)NVOX * CCH + t] = (bf16_t)0.0f;
        y1[(size_t)NVOX * CCH + t]    = (bf16_t)0.0f;
        y2[(size_t)NVOX * CCH + t]    = (bf16_t)0.0f;
    }
    for (int i = t; i < 768; i += 256) stats[i] = 0.0f;
}

// ---------- prep: W [27,Ci,Co] f32 -> W^T [layer][k][co][ci] bf16 ----------
__global__ void k_prep_w(const float* __restrict__ w0, const float* __restrict__ w1,
                         const float* __restrict__ w2, bf16_t* __restrict__ wbt) {
    int blk = blockIdx.x;                // 0..80
    int layer = blk / 27, k = blk % 27;
    const float* w = (layer == 0 ? w0 : (layer == 1 ? w1 : w2)) + k * 16384;
    __shared__ bf16_t tile[128][132];
    for (int e = threadIdx.x; e < 16384; e += 256) {
        int ci = e >> 7, co = e & 127;
        tile[co][ci] = (bf16_t)w[e];
    }
    __syncthreads();
    bf16_t* out = wbt + (size_t)blk * 16384;
    for (int e = threadIdx.x; e < 16384; e += 256) {
        int co = e >> 7, ci = e & 127;
        out[e] = tile[co][ci];
    }
}

// ---------- prep: rulebook per (block of 128 rows, tap k) ----------
// entry = (local_row << 18) | gather_idx ; pad entries = NVOX (zero row)
__global__ void k_prep_rule(const int* __restrict__ nbr, unsigned* __restrict__ rule,
                            int* __restrict__ cntTab) {
    __shared__ int snbr[128 * 27];       // 13.5KB
    __shared__ int c0s[4];
    const int b = blockIdx.x, tid = threadIdx.x, m0 = b << 7;
    for (int i = tid; i < 128 * 27; i += 256) snbr[i] = nbr[(size_t)m0 * 27 + i];
    __syncthreads();
    const int w = tid >> 6, l = tid & 63;
    for (int k = 0; k < 27; ++k) {
        int idx = 0; bool valid = false;
        if (tid < 128) { idx = snbr[tid * 27 + k]; valid = idx >= 0; }
        unsigned long long m = __ballot(valid);
        if (l == 0) c0s[w] = (int)__popcll(m);
        __syncthreads();
        int base = (w == 1) ? c0s[0] : 0;
        int total = c0s[0] + c0s[1];
        int prefix = (int)__popcll(m & ((1ull << l) - 1ull));
        unsigned* rk = rule + ((size_t)b * 27 + k) * 128;
        if (valid) rk[base + prefix] = ((unsigned)tid << 18) | (unsigned)idx;
        int nr = ((total + 15) >> 4) << 4;
        if (tid < nr - total) rk[total + tid] = (unsigned)NVOX;   // pad
        if (tid == 0) cntTab[b * 27 + k] = total;
        __syncthreads();
    }
}

// One pipeline step: prefetch A(p+1) (+B if next pass starts a new tap) into
// An/Bn, compute pass p from Ac/Bc, scatter-add into LDS accumulator.
// All register-array references are static (branch-duplicated at call site).
#define STEP(Ac, An, Bc, Bn)                                                    \
    {                                                                           \
        const int e = passLds[p];                                               \
        if (p + 1 < P) {                                                        \
            const int en = passLds[p + 1];                                      \
            const int kn = en & 31, tn = (en >> 5) & 7;                         \
            const unsigned* rkn = ruleB + (kn << 7) + (tn << 4);                \
            if (tn == 0) {                                                      \
                const char* wp = wbase + ((size_t)kn << 15) +                   \
                                 ((colbase + lrow) << 8) + (lq << 4);           \
                _Pragma("unroll")                                               \
                for (int jj = 0; jj < 2; ++jj) {                                \
                    _Pragma("unroll")                                           \
                    for (int c = 0; c < 4; ++c)                                 \
                        Bn[jj * 4 + c] =                                        \
                            *(const bf16x8*)(wp + jj * 4096 + c * 64);          \
                }                                                               \
            }                                                                   \
            unsigned enr = rkn[lrow];                                           \
            const char* ap = xb + ((size_t)(enr & 0x3FFFFu) << 8) + (lq << 4);  \
            _Pragma("unroll")                                                   \
            for (int c = 0; c < 4; ++c)                                         \
                An[c] = *(const bf16x8*)(ap + c * 64);                          \
        }                                                                       \
        f32x4 t0 = {0.f, 0.f, 0.f, 0.f}, t1 = {0.f, 0.f, 0.f, 0.f};             \
        _Pragma("unroll")                                                       \
        for (int c = 0; c < 4; ++c) {                                           \
            t0 = __builtin_amdgcn_mfma_f32_16x16x32_bf16(Ac[c], Bc[c], t0, 0, 0, 0);     \
            t1 = __builtin_amdgcn_mfma_f32_16x16x32_bf16(Ac[c], Bc[4 + c], t1, 0, 0, 0); \
        }                                                                       \
        const int kc = e & 31, tc = (e >> 5) & 7, cnt = e >> 10;                \
        const unsigned* rkc = ruleB + (kc << 7) + (tc << 4);                    \
        uint4 e4 = *(const uint4*)(rkc + (lq << 2));                            \
        const int rbase = (tc << 4) + (lq << 2);                                \
        const unsigned* ep = (const unsigned*)&e4;                              \
        _Pragma("unroll")                                                       \
        for (int r = 0; r < 4; ++r) {                                           \
            if (rbase + r < cnt) {                                              \
                int row = (int)(ep[r] >> 18);                                   \
                accf[accIdx(row, colbase + lrow)]      += t0[r];                \
                accf[accIdx(row, colbase + 16 + lrow)] += t1[r];                \
            }                                                                   \
        }                                                                       \
        ++p;                                                                    \
    }

// ---------- sparse conv: barrier-free register-pipelined gather-GEMM ----------
__global__ __launch_bounds__(256, 2) void k_conv_sp(
        const bf16_t* __restrict__ xin,     // (N+1) x 128 bf16
        const bf16_t* __restrict__ wbt,     // 27 x 128co x 128ci bf16
        const unsigned* __restrict__ rule,  // [1024][27][128]
        const int* __restrict__ cntTab,     // [1024][27]
        bf16_t* __restrict__ yout,          // N x 128 bf16
        float* __restrict__ stat)           // [0..127]=sum [128..255]=sumsq
{
    __shared__ __align__(16) float accf[128 * 128];   // 64KB swizzled
    __shared__ float ssum[128], ssq[128];
    __shared__ int cntLds[27];
    __shared__ int passLds[128];
    __shared__ int nPassS;

    const int tid = threadIdx.x;
    const int b = blockIdx.x;
    const int w = tid >> 6, l = tid & 63;
    const int lrow = l & 15, lq = l >> 4;
    const int colbase = w << 5;                       // wave owns 32 cols

    for (int i = tid; i < 128 * 128 / 4; i += 256)
        ((f32x4*)accf)[i] = (f32x4){0.f, 0.f, 0.f, 0.f};
    if (tid < 128) { ssum[tid] = 0.f; ssq[tid] = 0.f; }
    if (tid < 27) cntLds[tid] = cntTab[b * 27 + tid];
    __syncthreads();

    if (tid == 0) {
        int P = 0, bp = 0;
        for (int k = 0; k < 27; ++k) {
            int cnt = cntLds[k];
            if (!cnt) continue;
            bp ^= 1;
            int nt = (cnt + 15) >> 4;
            for (int t = 0; t < nt; ++t)
                passLds[P++] = k | (t << 5) | (bp << 9) | (cnt << 10);
        }
        nPassS = P;
    }
    __syncthreads();
    const int P = nPassS;

    const char* xb = (const char*)xin;
    const char* wbase = (const char*)wbt;
    const unsigned* ruleB = rule + (size_t)b * 27 * 128;

    bf16x8 A0[4], A1[4], B0[8], B1[8];

    // preload pass 0 (builder guarantees first tap has bp==1)
    if (P > 0) {
        const int e0 = passLds[0];
        const int k0 = e0 & 31;
        const char* wp = wbase + ((size_t)k0 << 15) + ((colbase + lrow) << 8) + (lq << 4);
        #pragma unroll
        for (int jj = 0; jj < 2; ++jj) {
            #pragma unroll
            for (int c = 0; c < 4; ++c)
                B1[jj * 4 + c] = *(const bf16x8*)(wp + jj * 4096 + c * 64);
        }
        const unsigned* rk0 = ruleB + (k0 << 7);
        unsigned en0 = rk0[lrow];
        const char* ap = xb + ((size_t)(en0 & 0x3FFFFu) << 8) + (lq << 4);
        #pragma unroll
        for (int c = 0; c < 4; ++c)
            A0[c] = *(const bf16x8*)(ap + c * 64);
    }

    int p = 0;
    while (p < P) {
        {
            const int bp = (passLds[p] >> 9) & 1;
            if (bp) { STEP(A0, A1, B1, B0) } else { STEP(A0, A1, B0, B1) }
        }
        if (p >= P) break;
        {
            const int bp = (passLds[p] >> 9) & 1;
            if (bp) { STEP(A1, A0, B1, B0) } else { STEP(A1, A0, B0, B1) }
        }
    }
    __syncthreads();

    // epilogue: bf16 store + channel stats (256 threads)
    float ps[8] = {0,0,0,0,0,0,0,0}, pq[8] = {0,0,0,0,0,0,0,0};
    const int cb = (tid & 15) << 3;
    bf16_t* yrow = yout + ((size_t)b << 7) * CCH;
    #pragma unroll
    for (int r = 0; r < 8; ++r) {
        int row = (r << 4) + (tid >> 4);
        bf16x8 o;
        #pragma unroll
        for (int i = 0; i < 8; ++i) {
            float v = accf[accIdx(row, cb + i)];
            o[i] = (bf16_t)v;
            ps[i] += v; pq[i] += v * v;
        }
        ((bf16x8*)yrow)[(row << 4) + (tid & 15)] = o;
    }
    #pragma unroll
    for (int i = 0; i < 8; ++i) {
        ps[i] += __shfl_xor(ps[i], 16, 64);
        ps[i] += __shfl_xor(ps[i], 32, 64);
        pq[i] += __shfl_xor(pq[i], 16, 64);
        pq[i] += __shfl_xor(pq[i], 32, 64);
    }
    if (lq == 0) {
        #pragma unroll
        for (int i = 0; i < 8; ++i) {
            atomicAdd(&ssum[cb + i], ps[i]);
            atomicAdd(&ssq[cb + i],  pq[i]);
        }
    }
    __syncthreads();
    if (tid < 128) {
        atomicAdd(&stat[tid],       ssum[tid]);
        atomicAdd(&stat[128 + tid], ssq[tid]);
    }
}

// ---------- BN + LeakyReLU, bf16 in -> bf16 out (in-place safe) ----------
__global__ void k_bnact(const bf16_t* __restrict__ x, const float* __restrict__ stat,
                        const float* __restrict__ g, const float* __restrict__ b,
                        bf16_t* __restrict__ out, float slope) {
    __shared__ float sc[128], sh[128];
    int tid = threadIdx.x;
    if (tid < 128) {
        float mu  = stat[tid] * (1.0f / NVOX);
        float var = stat[128 + tid] * (1.0f / NVOX) - mu * mu;
        float inv = rsqrtf(var + EPSV);
        float s = g[tid] * inv;
        sc[tid] = s;
        sh[tid] = b[tid] - mu * s;
    }
    __syncthreads();
    int i = blockIdx.x * 256 + tid;              // over N*C/8 = 2097152
    bf16x8 v = ((const bf16x8*)x)[i];
    int c = (i << 3) & 127;
    bf16x8 o;
    #pragma unroll
    for (int j = 0; j < 8; ++j) {
        float y = (float)v[j] * sc[c + j] + sh[c + j];
        y = y >= 0.0f ? y : slope * y;
        o[j] = (bf16_t)y;
    }
    ((bf16x8*)out)[i] = o;
}

// ---------- BN3 + residual + LeakyReLU(1/3) -> f32 d_out ----------
__global__ void k_final(const bf16_t* __restrict__ x, const float* __restrict__ stat,
                        const float* __restrict__ g, const float* __restrict__ b,
                        const bf16_t* __restrict__ res, float* __restrict__ out) {
    __shared__ float sc[128], sh[128];
    int tid = threadIdx.x;
    if (tid < 128) {
        float mu  = stat[tid] * (1.0f / NVOX);
        float var = stat[128 + tid] * (1.0f / NVOX) - mu * mu;
        float inv = rsqrtf(var + EPSV);
        float s = g[tid] * inv;
        sc[tid] = s;
        sh[tid] = b[tid] - mu * s;
    }
    __syncthreads();
    int i = blockIdx.x * 256 + tid;              // over N*C/8
    bf16x8 v = ((const bf16x8*)x)[i];
    bf16x8 r8 = ((const bf16x8*)res)[i];
    int c = (i << 3) & 127;
    const float k3 = 1.0f / 3.0f;
    float4 o0, o1;
    #pragma unroll
    for (int j = 0; j < 8; ++j) {
        float y = (float)v[j] * sc[c + j] + sh[c + j] + (float)r8[j];
        y = y >= 0.0f ? y : k3 * y;
        if (j < 4) ((float*)&o0)[j] = y; else ((float*)&o1)[j - 4] = y;
    }
    ((float4*)out)[2 * i]     = o0;
    ((float4*)out)[2 * i + 1] = o1;
}

extern "C" void kernel_launch(void* const* d_in, const int* in_sizes, int n_in,
                              void* d_out, int out_size, void* d_ws, size_t ws_size,
                              hipStream_t stream) {
    (void)in_sizes; (void)n_in; (void)out_size; (void)ws_size;
    const float* features = (const float*)d_in[0];
    const int*   nbr      = (const int*)d_in[1];
    const float* w1 = (const float*)d_in[2];
    const float* w2 = (const float*)d_in[3];
    const float* w3 = (const float*)d_in[4];
    const float* g1 = (const float*)d_in[5];
    const float* b1 = (const float*)d_in[6];
    const float* g2 = (const float*)d_in[7];
    const float* b2 = (const float*)d_in[8];
    const float* g3 = (const float*)d_in[9];
    const float* b3 = (const float*)d_in[10];

    char* ws = (char*)d_ws;
    const size_t SZ_FB = (size_t)(NVOX + 1) * CCH * 2;   // 33,554,688 B
    bf16_t*   featb  = (bf16_t*)(ws);
    bf16_t*   y1     = (bf16_t*)(ws + SZ_FB);
    bf16_t*   y2     = (bf16_t*)(ws + 2 * SZ_FB);
    bf16_t*   y3     = (bf16_t*)(ws + 3 * SZ_FB);
    bf16_t*   wbt    = (bf16_t*)(ws + 4 * SZ_FB);
    unsigned* rule   = (unsigned*)(ws + 4 * SZ_FB + 2654208);
    int*      cntTab = (int*)(ws + 4 * SZ_FB + 2654208 + 14155776);
    float*    stats  = (float*)(ws + 4 * SZ_FB + 2654208 + 14155776 + 110592);

    k_prep_feat<<<16384, 256, 0, stream>>>(features, featb);
    k_prep_misc<<<1, 256, 0, stream>>>(featb, y1, y2, stats);
    k_prep_w<<<81, 256, 0, stream>>>(w1, w2, w3, wbt);
    k_prep_rule<<<1024, 256, 0, stream>>>(nbr, rule, cntTab);

    k_conv_sp<<<1024, 256, 0, stream>>>(featb, wbt, rule, cntTab, y1, stats);
    k_bnact<<<8192, 256, 0, stream>>>(y1, stats, g1, b1, y1, 0.05f);

    k_conv_sp<<<1024, 256, 0, stream>>>(y1, wbt + (size_t)27 * 16384, rule, cntTab, y2, stats + 256);
    k_bnact<<<8192, 256, 0, stream>>>(y2, stats + 256, g2, b2, y2, 0.05f);

    k_conv_sp<<<1024, 256, 0, stream>>>(y2, wbt + (size_t)54 * 16384, rule, cntTab, y3, stats + 512);
    k_final<<<8192, 256, 0, stream>>>(y3, stats + 512, g3, b3, y1, (float*)d_out);
}